// Round 1
// baseline (103.457 us; speedup 1.0000x reference)
//
#include <hip/hip_runtime.h>
#include <math.h>

constexpr int D  = 768;
constexpr int NQ = 8;
constexpr int B  = 32;
constexpr int NP = 196;   // n_patch
constexpr float EPS = 1e-5f;
constexpr float INV_SQRT_D = 0.036084391824351615f;  // 1/sqrt(768)

__device__ __forceinline__ float wave_reduce_sum(float v) {
#pragma unroll
    for (int off = 32; off > 0; off >>= 1) v += __shfl_xor(v, off, 64);
    return v;
}
__device__ __forceinline__ float wave_reduce_max(float v) {
#pragma unroll
    for (int off = 32; off > 0; off >>= 1) v = fmaxf(v, __shfl_xor(v, off, 64));
    return v;
}

// One block per row of length D=768; 256 threads, 3 elems/thread.
__global__ __launch_bounds__(256) void ln_kernel(const float* __restrict__ x,
                                                 const float* __restrict__ w,
                                                 const float* __restrict__ bias,
                                                 float* __restrict__ y) {
    const int row = blockIdx.x;
    const int tid = threadIdx.x;
    const float* xr = x + (size_t)row * D;
    float* yr = y + (size_t)row * D;

    float v0 = xr[tid], v1 = xr[tid + 256], v2 = xr[tid + 512];

    __shared__ float red[4];
    const int wid = tid >> 6, lane = tid & 63;

    float s = wave_reduce_sum(v0 + v1 + v2);
    if (lane == 0) red[wid] = s;
    __syncthreads();
    const float mean = (red[0] + red[1] + red[2] + red[3]) * (1.0f / D);
    __syncthreads();

    const float d0 = v0 - mean, d1 = v1 - mean, d2 = v2 - mean;
    float ss = wave_reduce_sum(d0 * d0 + d1 * d1 + d2 * d2);
    if (lane == 0) red[wid] = ss;
    __syncthreads();
    const float var = (red[0] + red[1] + red[2] + red[3]) * (1.0f / D);
    const float rs = rsqrtf(var + EPS);

    yr[tid]       = d0 * rs * w[tid]       + bias[tid];
    yr[tid + 256] = d1 * rs * w[tid + 256] + bias[tid + 256];
    yr[tid + 512] = d2 * rs * w[tid + 512] + bias[tid + 512];
}

// S[b][q][n] = qn[q] . kvn[b,n] / sqrt(D).  One block per (b,n) row.
__global__ __launch_bounds__(256) void scores_kernel(const float* __restrict__ kvn,
                                                     const float* __restrict__ qn,
                                                     float* __restrict__ S) {
    const int row = blockIdx.x;       // row = b*NP + n
    const int tid = threadIdx.x;
    const float* kr = kvn + (size_t)row * D;
    const float k0 = kr[tid], k1 = kr[tid + 256], k2 = kr[tid + 512];

    float part[NQ];
#pragma unroll
    for (int q = 0; q < NQ; ++q) {
        part[q] = k0 * qn[q * D + tid] + k1 * qn[q * D + tid + 256] +
                  k2 * qn[q * D + tid + 512];
    }

    __shared__ float red[NQ][4];
    const int wid = tid >> 6, lane = tid & 63;
#pragma unroll
    for (int q = 0; q < NQ; ++q) {
        float s = wave_reduce_sum(part[q]);
        if (lane == 0) red[q][wid] = s;
    }
    __syncthreads();
    if (tid < NQ) {
        const int b = row / NP, n = row - b * NP;
        const float v =
            (red[tid][0] + red[tid][1] + red[tid][2] + red[tid][3]) * INV_SQRT_D;
        S[((size_t)b * NQ + tid) * NP + n] = v;
    }
}

// One block per pair p = i*32 + j. Softmax of (S_i - S_j) rows, then
// out[p,q,:] = sum_n a[q][n] * (kvn[i,n,:] - kvn[j,n,:]).
__global__ __launch_bounds__(256) void attn_kernel(const float* __restrict__ kvn,
                                                   const float* __restrict__ S,
                                                   float* __restrict__ out) {
    const int p = blockIdx.x;
    const int i = p >> 5, j = p & 31;
    const int tid = threadIdx.x;

    __shared__ float a[NQ][NP];
    const float* Si = S + (size_t)i * NQ * NP;
    const float* Sj = S + (size_t)j * NQ * NP;
    for (int idx = tid; idx < NQ * NP; idx += 256)
        (&a[0][0])[idx] = Si[idx] - Sj[idx];
    __syncthreads();

    const int wid = tid >> 6, lane = tid & 63;
#pragma unroll
    for (int qq = 0; qq < 2; ++qq) {
        const int q = wid * 2 + qq;
        float m = -1e30f;
        for (int n = lane; n < NP; n += 64) m = fmaxf(m, a[q][n]);
        m = wave_reduce_max(m);
        float s = 0.f;
        for (int n = lane; n < NP; n += 64) {
            const float e = __expf(a[q][n] - m);
            a[q][n] = e;
            s += e;
        }
        s = wave_reduce_sum(s);
        const float rinv = 1.0f / s;
        for (int n = lane; n < NP; n += 64) a[q][n] *= rinv;
    }
    __syncthreads();

    const float* kvi = kvn + (size_t)i * NP * D;
    const float* kvj = kvn + (size_t)j * NP * D;

    float acc[NQ][3];
#pragma unroll
    for (int q = 0; q < NQ; ++q)
        for (int c = 0; c < 3; ++c) acc[q][c] = 0.f;

    for (int n = 0; n < NP; ++n) {
        const float di0 = kvi[n * D + tid]       - kvj[n * D + tid];
        const float di1 = kvi[n * D + tid + 256] - kvj[n * D + tid + 256];
        const float di2 = kvi[n * D + tid + 512] - kvj[n * D + tid + 512];
#pragma unroll
        for (int q = 0; q < NQ; ++q) {
            const float wgt = a[q][n];
            acc[q][0] = fmaf(wgt, di0, acc[q][0]);
            acc[q][1] = fmaf(wgt, di1, acc[q][1]);
            acc[q][2] = fmaf(wgt, di2, acc[q][2]);
        }
    }

    float* op = out + (size_t)p * NQ * D;
#pragma unroll
    for (int q = 0; q < NQ; ++q) {
        op[q * D + tid]       = acc[q][0];
        op[q * D + tid + 256] = acc[q][1];
        op[q * D + tid + 512] = acc[q][2];
    }
}

extern "C" void kernel_launch(void* const* d_in, const int* in_sizes, int n_in,
                              void* d_out, int out_size, void* d_ws, size_t ws_size,
                              hipStream_t stream) {
    const float* q_x     = (const float*)d_in[0];
    const float* kv_x    = (const float*)d_in[1];
    const float* ln_q_w  = (const float*)d_in[2];
    const float* ln_q_b  = (const float*)d_in[3];
    const float* ln_kv_w = (const float*)d_in[4];
    const float* ln_kv_b = (const float*)d_in[5];
    float* out = (float*)d_out;

    float* ws  = (float*)d_ws;
    float* qn  = ws;                                // 8*768
    float* kvn = ws + NQ * D;                       // 32*196*768
    float* S   = kvn + (size_t)B * NP * D;          // 32*8*196

    ln_kernel<<<NQ, 256, 0, stream>>>(q_x, ln_q_w, ln_q_b, qn);
    ln_kernel<<<B * NP, 256, 0, stream>>>(kv_x, ln_kv_w, ln_kv_b, kvn);
    scores_kernel<<<B * NP, 256, 0, stream>>>(kvn, qn, S);
    attn_kernel<<<B * B, 256, 0, stream>>>(kvn, S, out);
}

// Round 2
// 72.551 us; speedup vs baseline: 1.4260x; 1.4260x over previous
//
#include <hip/hip_runtime.h>
#include <math.h>

constexpr int D  = 768;
constexpr int NQ = 8;
constexpr int B  = 32;
constexpr int NP = 196;   // n_patch
constexpr int KT = 7;     // K tiles of 32
constexpr int KP = KT * 32;  // 224 padded K
constexpr int PSTR = 228;    // P row stride in floats (16B-aligned, odd/32 banks)
constexpr float EPS = 1e-5f;
constexpr float INV_SQRT_D = 0.036084391824351615f;  // 1/sqrt(768)

typedef __attribute__((ext_vector_type(8))) short short8;
typedef __attribute__((ext_vector_type(4))) float f32x4;

__device__ __forceinline__ float wave_reduce_sum(float v) {
#pragma unroll
    for (int off = 32; off > 0; off >>= 1) v += __shfl_xor(v, off, 64);
    return v;
}
__device__ __forceinline__ float wave_reduce_max(float v) {
#pragma unroll
    for (int off = 32; off > 0; off >>= 1) v = fmaxf(v, __shfl_xor(v, off, 64));
    return v;
}

__device__ __forceinline__ unsigned short f2bf(float x) {
    union { float f; unsigned u; } c; c.f = x;
    unsigned r = c.u + 0x7fffu + ((c.u >> 16) & 1u);   // RNE
    return (unsigned short)(r >> 16);
}

// LayerNorm one row of D=768 per block; 256 threads, 3 elems/thread.
__global__ __launch_bounds__(256) void ln_kernel(const float* __restrict__ x,
                                                 const float* __restrict__ w,
                                                 const float* __restrict__ bias,
                                                 float* __restrict__ y) {
    const int row = blockIdx.x;
    const int tid = threadIdx.x;
    const float* xr = x + (size_t)row * D;
    float* yr = y + (size_t)row * D;

    float v0 = xr[tid], v1 = xr[tid + 256], v2 = xr[tid + 512];

    __shared__ float red[4];
    const int wid = tid >> 6, lane = tid & 63;

    float s = wave_reduce_sum(v0 + v1 + v2);
    if (lane == 0) red[wid] = s;
    __syncthreads();
    const float mean = (red[0] + red[1] + red[2] + red[3]) * (1.0f / D);
    __syncthreads();

    const float d0 = v0 - mean, d1 = v1 - mean, d2 = v2 - mean;
    float ss = wave_reduce_sum(d0 * d0 + d1 * d1 + d2 * d2);
    if (lane == 0) red[wid] = ss;
    __syncthreads();
    const float var = (red[0] + red[1] + red[2] + red[3]) * (1.0f / D);
    const float rs = rsqrtf(var + EPS);

    yr[tid]       = d0 * rs * w[tid]       + bias[tid];
    yr[tid + 256] = d1 * rs * w[tid + 256] + bias[tid + 256];
    yr[tid + 512] = d2 * rs * w[tid + 512] + bias[tid + 512];
}

// Fused: LN(kv rows) + scores S[b][q][n] + bf16 transpose pack kvT[b][d][KP].
// One block per (b, ktile): 32 rows of n. 512 threads = 8 waves, 4 rows/wave.
__global__ __launch_bounds__(512) void kv_fused(const float* __restrict__ kv_x,
                                                const float* __restrict__ w,
                                                const float* __restrict__ bias,
                                                const float* __restrict__ qn,
                                                float* __restrict__ S,
                                                unsigned short* __restrict__ kvT) {
    const int b  = blockIdx.x / KT;
    const int kt = blockIdx.x % KT;
    const int tid = threadIdx.x, wave = tid >> 6, lane = tid & 63;
    __shared__ unsigned short tile[32][D];  // 48 KB bf16

    // preload qn into registers (stride-64 coalesced; L1-hot across blocks)
    float qreg[NQ][12];
#pragma unroll
    for (int q = 0; q < NQ; ++q)
#pragma unroll
        for (int c = 0; c < 12; ++c) qreg[q][c] = qn[q * D + lane + 64 * c];

    for (int r = 0; r < 4; ++r) {
        const int nl = wave * 4 + r;
        const int n  = kt * 32 + nl;
        if (n < NP) {
            const float* xr = kv_x + ((size_t)b * NP + n) * D;
            float v[12];
            float s = 0.f;
#pragma unroll
            for (int c = 0; c < 12; ++c) { v[c] = xr[lane + 64 * c]; s += v[c]; }
            s = wave_reduce_sum(s);
            const float mean = s * (1.0f / D);
            float ss = 0.f;
#pragma unroll
            for (int c = 0; c < 12; ++c) { v[c] -= mean; ss += v[c] * v[c]; }
            ss = wave_reduce_sum(ss);
            const float rs = rsqrtf(ss * (1.0f / D) + EPS);
            float y[12];
#pragma unroll
            for (int c = 0; c < 12; ++c) {
                const int d = lane + 64 * c;
                y[c] = v[c] * rs * w[d] + bias[d];
                tile[nl][d] = f2bf(y[c]);
            }
#pragma unroll
            for (int q = 0; q < NQ; ++q) {
                float dq = 0.f;
#pragma unroll
                for (int c = 0; c < 12; ++c) dq += y[c] * qreg[q][c];
                dq = wave_reduce_sum(dq);
                if (lane == 0) S[((size_t)b * NQ + q) * NP + n] = dq * INV_SQRT_D;
            }
        } else {
#pragma unroll
            for (int c = 0; c < 12; ++c) tile[nl][lane + 64 * c] = 0;
        }
    }
    __syncthreads();

    // transpose write: kvT[b][d][kt*32 .. kt*32+32)  (64B per d, coalesced)
    for (int d = tid; d < D; d += 512) {
        unsigned pack[16];
#pragma unroll
        for (int g = 0; g < 16; ++g) {
            unsigned lo = tile[2 * g][d], hi = tile[2 * g + 1][d];
            pack[g] = lo | (hi << 16);
        }
        uint4* dst = (uint4*)(kvT + ((size_t)b * D + d) * KP + kt * 32);
        const uint4* src = (const uint4*)pack;
#pragma unroll
        for (int g = 0; g < 4; ++g) dst[g] = src[g];
    }
}

// Diagonal pairs (i,i): kv_pair == 0 -> output exactly 0.
__global__ __launch_bounds__(256) void zero_diag(float* __restrict__ out) {
    const int i = blockIdx.x;
    f32x4* dst = (f32x4*)(out + (size_t)(i * B + i) * NQ * D);
    for (int t = threadIdx.x; t < NQ * D / 4; t += 256) {
        f32x4 z = {0.f, 0.f, 0.f, 0.f};
        dst[t] = z;
    }
}

// One block per unordered pair {i<j}: computes O_ij and O_ji via bf16 MFMA.
// O_ij = P_ij @ kvi - P_ij @ kvj ; O_ji = P_ji @ kvj - P_ji @ kvi.
__global__ __launch_bounds__(256) void attn_mfma(const float* __restrict__ S,
                                                 const unsigned short* __restrict__ kvT,
                                                 float* __restrict__ out) {
    int idx = blockIdx.x, i = 0;
    while (idx >= 31 - i) { idx -= 31 - i; ++i; }
    const int j = i + 1 + idx;

    const int tid = threadIdx.x, wave = tid >> 6, lane = tid & 63;
    __shared__ float P[2][16][PSTR];  // 29.2 KB; rows 8..15 zero (M-pad)

    const float* Si = S + (size_t)i * NQ * NP;
    const float* Sj = S + (size_t)j * NQ * NP;
    for (int t = tid; t < 16 * PSTR; t += 256) {
        const int q = t / PSTR, n = t - q * PSTR;
        float d0 = 0.f, d1 = 0.f;
        if (q < NQ) {
            if (n < NP) { const float dv = Si[q * NP + n] - Sj[q * NP + n]; d0 = dv; d1 = -dv; }
            else        { d0 = -1e30f; d1 = -1e30f; }   // K-pad -> weight 0
        }
        P[0][q][n] = d0;
        P[1][q][n] = d1;
    }
    __syncthreads();

    // softmax over 16 rows (2 dirs x 8 q); 4 rows per wave, in place
    for (int jj = 0; jj < 4; ++jj) {
        const int job = wave * 4 + jj, dir = job >> 3, q = job & 7;
        float* row = &P[dir][q][0];
        float m = -1e30f;
#pragma unroll
        for (int c = 0; c < 4; ++c) { const int n = lane + 64 * c; if (n < KP) m = fmaxf(m, row[n]); }
        m = wave_reduce_max(m);
        float e[4] = {0.f, 0.f, 0.f, 0.f};
        float sum = 0.f;
#pragma unroll
        for (int c = 0; c < 4; ++c) { const int n = lane + 64 * c; if (n < KP) { e[c] = __expf(row[n] - m); sum += e[c]; } }
        sum = wave_reduce_sum(sum);
        const float rinv = 1.0f / sum;
#pragma unroll
        for (int c = 0; c < 4; ++c) { const int n = lane + 64 * c; if (n < KP) row[n] = e[c] * rinv; }
    }
    __syncthreads();

    const int dlow = lane & 15, kgrp = lane >> 4;
    const unsigned short* kvTi = kvT + (size_t)i * D * KP;
    const unsigned short* kvTj = kvT + (size_t)j * D * KP;

    f32x4 acc_ij[12], acc_ji[12];
#pragma unroll
    for (int t = 0; t < 12; ++t) {
        f32x4 z = {0.f, 0.f, 0.f, 0.f};
        acc_ij[t] = z; acc_ji[t] = z;
    }

    for (int kt = 0; kt < KT; ++kt) {
        // A-fragments from LDS softmax rows: lane -> (r=dlow, k=kt*32+kgrp*8+e)
        const float* p0 = &P[0][dlow][kt * 32 + kgrp * 8];
        const float* p1 = &P[1][dlow][kt * 32 + kgrp * 8];
        f32x4 a0lo = *(const f32x4*)p0, a0hi = *(const f32x4*)(p0 + 4);
        f32x4 a1lo = *(const f32x4*)p1, a1hi = *(const f32x4*)(p1 + 4);
        short8 Aij, nAij, Aji, nAji;
#pragma unroll
        for (int e = 0; e < 4; ++e) {
            unsigned short b0 = f2bf(a0lo[e]);
            Aij[e]  = (short)b0;  nAij[e]  = (short)(b0 ^ 0x8000u);
            unsigned short b1 = f2bf(a0hi[e]);
            Aij[e+4] = (short)b1; nAij[e+4] = (short)(b1 ^ 0x8000u);
            unsigned short c0 = f2bf(a1lo[e]);
            Aji[e]  = (short)c0;  nAji[e]  = (short)(c0 ^ 0x8000u);
            unsigned short c1 = f2bf(a1hi[e]);
            Aji[e+4] = (short)c1; nAji[e+4] = (short)(c1 ^ 0x8000u);
        }
        const int koff = kt * 32 + kgrp * 8;
#pragma unroll
        for (int t = 0; t < 12; ++t) {
            const int nt = wave * 12 + t;
            const int eo = (nt * 16 + dlow) * KP + koff;
            short8 Bi = *(const short8*)(kvTi + eo);
            short8 Bj = *(const short8*)(kvTj + eo);
            acc_ij[t] = __builtin_amdgcn_mfma_f32_16x16x32_bf16(Aij,  Bi, acc_ij[t], 0, 0, 0);
            acc_ij[t] = __builtin_amdgcn_mfma_f32_16x16x32_bf16(nAij, Bj, acc_ij[t], 0, 0, 0);
            acc_ji[t] = __builtin_amdgcn_mfma_f32_16x16x32_bf16(Aji,  Bj, acc_ji[t], 0, 0, 0);
            acc_ji[t] = __builtin_amdgcn_mfma_f32_16x16x32_bf16(nAji, Bi, acc_ji[t], 0, 0, 0);
        }
    }

    // C layout: col = lane&15, row = (lane>>4)*4 + reg; rows 0..7 valid
    if (kgrp < 2) {
        float* Oij = out + (size_t)(i * B + j) * NQ * D;
        float* Oji = out + (size_t)(j * B + i) * NQ * D;
#pragma unroll
        for (int t = 0; t < 12; ++t) {
            const int d = wave * 192 + t * 16 + dlow;
#pragma unroll
            for (int r = 0; r < 4; ++r) {
                Oij[(kgrp * 4 + r) * D + d] = acc_ij[t][r];
                Oji[(kgrp * 4 + r) * D + d] = acc_ji[t][r];
            }
        }
    }
}

extern "C" void kernel_launch(void* const* d_in, const int* in_sizes, int n_in,
                              void* d_out, int out_size, void* d_ws, size_t ws_size,
                              hipStream_t stream) {
    const float* q_x     = (const float*)d_in[0];
    const float* kv_x    = (const float*)d_in[1];
    const float* ln_q_w  = (const float*)d_in[2];
    const float* ln_q_b  = (const float*)d_in[3];
    const float* ln_kv_w = (const float*)d_in[4];
    const float* ln_kv_b = (const float*)d_in[5];
    float* out = (float*)d_out;

    float* ws = (float*)d_ws;
    float* qn = ws;                               // 8*768 f32
    float* S  = ws + NQ * D;                      // 32*8*196 f32
    unsigned short* kvT = (unsigned short*)(ws + NQ * D + B * NQ * NP);  // 32*768*224 bf16

    ln_kernel<<<NQ, 256, 0, stream>>>(q_x, ln_q_w, ln_q_b, qn);
    kv_fused<<<B * KT, 512, 0, stream>>>(kv_x, ln_kv_w, ln_kv_b, qn, S, kvT);
    zero_diag<<<B, 256, 0, stream>>>(out);
    attn_mfma<<<(B * (B - 1)) / 2, 256, 0, stream>>>(S, kvT, out);
}

// Round 4
// 67.147 us; speedup vs baseline: 1.5408x; 1.0805x over previous
//
#include <hip/hip_runtime.h>
#include <math.h>

constexpr int D  = 768;
constexpr int NQ = 8;
constexpr int B  = 32;
constexpr int NP = 196;      // n_patch
constexpr int KT = 7;        // K tiles of 32
constexpr int KP = KT * 32;  // 224 padded K
constexpr float EPS = 1e-5f;
constexpr float INV_SQRT_D = 0.036084391824351615f;  // 1/sqrt(768)

typedef __attribute__((ext_vector_type(8))) short short8;
typedef __attribute__((ext_vector_type(4))) float f32x4;

__device__ __forceinline__ float wave_reduce_sum(float v) {
#pragma unroll
    for (int off = 32; off > 0; off >>= 1) v += __shfl_xor(v, off, 64);
    return v;
}
__device__ __forceinline__ float wave_reduce_max(float v) {
#pragma unroll
    for (int off = 32; off > 0; off >>= 1) v = fmaxf(v, __shfl_xor(v, off, 64));
    return v;
}

__device__ __forceinline__ unsigned short f2bf(float x) {
    union { float f; unsigned u; } c; c.f = x;
    unsigned r = c.u + 0x7fffu + ((c.u >> 16) & 1u);   // RNE
    return (unsigned short)(r >> 16);
}

// LayerNorm one row of D=768 per block; 256 threads, 3 elems/thread.
__global__ __launch_bounds__(256) void ln_kernel(const float* __restrict__ x,
                                                 const float* __restrict__ w,
                                                 const float* __restrict__ bias,
                                                 float* __restrict__ y) {
    const int row = blockIdx.x;
    const int tid = threadIdx.x;
    const float* xr = x + (size_t)row * D;
    float* yr = y + (size_t)row * D;

    float v0 = xr[tid], v1 = xr[tid + 256], v2 = xr[tid + 512];

    __shared__ float red[4];
    const int wid = tid >> 6, lane = tid & 63;

    float s = wave_reduce_sum(v0 + v1 + v2);
    if (lane == 0) red[wid] = s;
    __syncthreads();
    const float mean = (red[0] + red[1] + red[2] + red[3]) * (1.0f / D);
    __syncthreads();

    const float d0 = v0 - mean, d1 = v1 - mean, d2 = v2 - mean;
    float ss = wave_reduce_sum(d0 * d0 + d1 * d1 + d2 * d2);
    if (lane == 0) red[wid] = ss;
    __syncthreads();
    const float var = (red[0] + red[1] + red[2] + red[3]) * (1.0f / D);
    const float rs = rsqrtf(var + EPS);

    yr[tid]       = d0 * rs * w[tid]       + bias[tid];
    yr[tid + 256] = d1 * rs * w[tid + 256] + bias[tid + 256];
    yr[tid + 512] = d2 * rs * w[tid + 512] + bias[tid + 512];
}

// Fused: LN(kv rows) + scores S[b][q][n] + bf16 transpose pack kvT[b][d][KP].
// One block per (b, ktile): 32 rows of n. 512 threads = 8 waves, 4 rows/wave.
__global__ __launch_bounds__(512) void kv_fused(const float* __restrict__ kv_x,
                                                const float* __restrict__ w,
                                                const float* __restrict__ bias,
                                                const float* __restrict__ qn,
                                                float* __restrict__ S,
                                                unsigned short* __restrict__ kvT) {
    const int b  = blockIdx.x / KT;
    const int kt = blockIdx.x % KT;
    const int tid = threadIdx.x, wave = tid >> 6, lane = tid & 63;
    __shared__ unsigned short tile[32][D];  // 48 KB bf16

    float qreg[NQ][12];
#pragma unroll
    for (int q = 0; q < NQ; ++q)
#pragma unroll
        for (int c = 0; c < 12; ++c) qreg[q][c] = qn[q * D + lane + 64 * c];

    for (int r = 0; r < 4; ++r) {
        const int nl = wave * 4 + r;
        const int n  = kt * 32 + nl;
        if (n < NP) {
            const float* xr = kv_x + ((size_t)b * NP + n) * D;
            float v[12];
            float s = 0.f;
#pragma unroll
            for (int c = 0; c < 12; ++c) { v[c] = xr[lane + 64 * c]; s += v[c]; }
            s = wave_reduce_sum(s);
            const float mean = s * (1.0f / D);
            float ss = 0.f;
#pragma unroll
            for (int c = 0; c < 12; ++c) { v[c] -= mean; ss += v[c] * v[c]; }
            ss = wave_reduce_sum(ss);
            const float rs = rsqrtf(ss * (1.0f / D) + EPS);
            float y[12];
#pragma unroll
            for (int c = 0; c < 12; ++c) {
                const int d = lane + 64 * c;
                y[c] = v[c] * rs * w[d] + bias[d];
                tile[nl][d] = f2bf(y[c]);
            }
#pragma unroll
            for (int q = 0; q < NQ; ++q) {
                float dq = 0.f;
#pragma unroll
                for (int c = 0; c < 12; ++c) dq += y[c] * qreg[q][c];
                dq = wave_reduce_sum(dq);
                if (lane == 0) S[((size_t)b * NQ + q) * NP + n] = dq * INV_SQRT_D;
            }
        } else {
#pragma unroll
            for (int c = 0; c < 12; ++c) tile[nl][lane + 64 * c] = 0;
        }
    }
    __syncthreads();

    for (int d = tid; d < D; d += 512) {
        unsigned pack[16];
#pragma unroll
        for (int g = 0; g < 16; ++g) {
            unsigned lo = tile[2 * g][d], hi = tile[2 * g + 1][d];
            pack[g] = lo | (hi << 16);
        }
        uint4* dst = (uint4*)(kvT + ((size_t)b * D + d) * KP + kt * 32);
        const uint4* src = (const uint4*)pack;
#pragma unroll
        for (int g = 0; g < 4; ++g) dst[g] = src[g];
    }
}

// Softmax prep: Abf[p][q][KP] bf16, rows softmax(S_i - S_j), K-pad zeroed.
// One block per ordered pair p; 4 waves x 2 q-rows.
__global__ __launch_bounds__(256) void aprep(const float* __restrict__ S,
                                             unsigned short* __restrict__ Abf) {
    const int p = blockIdx.x, i = p >> 5, j = p & 31;
    const int tid = threadIdx.x, wave = tid >> 6, lane = tid & 63;

    for (int rr = 0; rr < 2; ++rr) {
        const int q = wave * 2 + rr;
        const float* Si = S + ((size_t)i * NQ + q) * NP;
        const float* Sj = S + ((size_t)j * NQ + q) * NP;
        float v[4];
        float m = -1e30f;
#pragma unroll
        for (int c = 0; c < 4; ++c) {
            const int n = lane + 64 * c;
            v[c] = (n < NP) ? (Si[n] - Sj[n]) : -1e30f;
            m = fmaxf(m, v[c]);
        }
        m = wave_reduce_max(m);
        float e[4];
        float sum = 0.f;
#pragma unroll
        for (int c = 0; c < 4; ++c) {
            const int n = lane + 64 * c;
            e[c] = (n < NP) ? __expf(v[c] - m) : 0.f;
            sum += e[c];
        }
        sum = wave_reduce_sum(sum);
        const float rinv = 1.0f / sum;
        unsigned short* arow = Abf + ((size_t)p * NQ + q) * KP;
#pragma unroll
        for (int c = 0; c < 4; ++c) {
            const int n = lane + 64 * c;
            if (n < KP) arow[n] = (n < NP) ? f2bf(e[c] * rinv) : (unsigned short)0;
        }
    }
}

// Stacked-pair GEMM. pass 0: for b=i, out[i*256+r] = A-rows @ kvT[i].
// pass 1: for b=j, out[row] -= A-rows @ kvT[j].  M=256, K=224, N=96 per block.
// 8 waves (512 thr): wave tile 64x48 = 4x3 fragments.
__global__ __launch_bounds__(512) void pair_gemm(const unsigned short* __restrict__ Abf,
                                                 const unsigned short* __restrict__ kvT,
                                                 float* __restrict__ out, int pass) {
    const int b  = blockIdx.x >> 3;
    const int ns = blockIdx.x & 7;
    const int tid = threadIdx.x, wave = tid >> 6, lane = tid & 63;
    const int wm = wave & 3, wn = wave >> 2;
    const int dlow = lane & 15, kgrp = lane >> 4;  // kgrp in [0,4)
    const int d0 = ns * 96 + wn * 48;

    const unsigned short* aptr[4];
#pragma unroll
    for (int m = 0; m < 4; ++m) {
        const int r = wm * 64 + m * 16 + dlow;
        const int arow = (pass == 0) ? (b * 256 + r)
                                     : (((r >> 3) * B + b) * NQ + (r & 7));
        aptr[m] = Abf + (size_t)arow * KP + kgrp * 8;
    }
    const unsigned short* bptr[3];
#pragma unroll
    for (int n = 0; n < 3; ++n)
        bptr[n] = kvT + ((size_t)b * D + d0 + n * 16 + dlow) * KP + kgrp * 8;

    f32x4 acc[4][3];
#pragma unroll
    for (int m = 0; m < 4; ++m)
#pragma unroll
        for (int n = 0; n < 3; ++n) {
            f32x4 z = {0.f, 0.f, 0.f, 0.f};
            acc[m][n] = z;
        }

    short8 Af[4], Bf[3];
#pragma unroll
    for (int m = 0; m < 4; ++m) Af[m] = *(const short8*)(aptr[m]);
#pragma unroll
    for (int n = 0; n < 3; ++n) Bf[n] = *(const short8*)(bptr[n]);

#pragma unroll
    for (int kt = 0; kt < KT; ++kt) {
        short8 An[4], Bn[3];
        if (kt + 1 < KT) {
            const int ko = (kt + 1) * 32;
#pragma unroll
            for (int m = 0; m < 4; ++m) An[m] = *(const short8*)(aptr[m] + ko);
#pragma unroll
            for (int n = 0; n < 3; ++n) Bn[n] = *(const short8*)(bptr[n] + ko);
        }
#pragma unroll
        for (int m = 0; m < 4; ++m)
#pragma unroll
            for (int n = 0; n < 3; ++n)
                acc[m][n] = __builtin_amdgcn_mfma_f32_16x16x32_bf16(Af[m], Bf[n], acc[m][n], 0, 0, 0);
        if (kt + 1 < KT) {
#pragma unroll
            for (int m = 0; m < 4; ++m) Af[m] = An[m];
#pragma unroll
            for (int n = 0; n < 3; ++n) Bf[n] = Bn[n];
        }
    }

    // C layout: col = lane&15 (d), row-in-frag = (lane>>4)*4 + reg
#pragma unroll
    for (int m = 0; m < 4; ++m) {
#pragma unroll
        for (int reg = 0; reg < 4; ++reg) {
            const int r = wm * 64 + m * 16 + kgrp * 4 + reg;
            const int arow = (pass == 0) ? (b * 256 + r)
                                         : (((r >> 3) * B + b) * NQ + (r & 7));
            float* op = out + (size_t)arow * D + d0 + dlow;
            if (pass == 0) {
#pragma unroll
                for (int n = 0; n < 3; ++n) op[n * 16] = acc[m][n][reg];
            } else {
#pragma unroll
                for (int n = 0; n < 3; ++n) op[n * 16] = op[n * 16] - acc[m][n][reg];
            }
        }
    }
}

extern "C" void kernel_launch(void* const* d_in, const int* in_sizes, int n_in,
                              void* d_out, int out_size, void* d_ws, size_t ws_size,
                              hipStream_t stream) {
    const float* q_x     = (const float*)d_in[0];
    const float* kv_x    = (const float*)d_in[1];
    const float* ln_q_w  = (const float*)d_in[2];
    const float* ln_q_b  = (const float*)d_in[3];
    const float* ln_kv_w = (const float*)d_in[4];
    const float* ln_kv_b = (const float*)d_in[5];
    float* out = (float*)d_out;

    float* ws = (float*)d_ws;
    float* qn = ws;                               // 8*768 f32
    float* S  = ws + NQ * D;                      // 32*8*196 f32
    unsigned short* kvT = (unsigned short*)(ws + NQ * D + B * NQ * NP);  // 32*768*224 bf16
    unsigned short* Abf = kvT + (size_t)B * D * KP;                      // 1024*8*224 bf16

    ln_kernel<<<NQ, 256, 0, stream>>>(q_x, ln_q_w, ln_q_b, qn);
    kv_fused<<<B * KT, 512, 0, stream>>>(kv_x, ln_kv_w, ln_kv_b, qn, S, kvT);
    aprep<<<B * B, 256, 0, stream>>>(S, Abf);
    pair_gemm<<<B * 8, 512, 0, stream>>>(Abf, kvT, out, 0);
    pair_gemm<<<B * 8, 512, 0, stream>>>(Abf, kvT, out, 1);
}

// Round 5
// 59.598 us; speedup vs baseline: 1.7359x; 1.1267x over previous
//
#include <hip/hip_runtime.h>
#include <math.h>

constexpr int D  = 768;
constexpr int NQ = 8;
constexpr int B  = 32;
constexpr int NP = 196;      // n_patch
constexpr int KT = 7;        // K tiles of 32
constexpr int KP = KT * 32;  // 224 padded K
constexpr int TPAD = 776;    // LDS tile row stride (shorts)
constexpr float EPS = 1e-5f;
constexpr float INV_SQRT_D = 0.036084391824351615f;  // 1/sqrt(768)

typedef __attribute__((ext_vector_type(8))) short short8;
typedef __attribute__((ext_vector_type(4))) float f32x4;

__device__ __forceinline__ float wave_reduce_sum(float v) {
#pragma unroll
    for (int off = 32; off > 0; off >>= 1) v += __shfl_xor(v, off, 64);
    return v;
}
__device__ __forceinline__ float wave_reduce_max(float v) {
#pragma unroll
    for (int off = 32; off > 0; off >>= 1) v = fmaxf(v, __shfl_xor(v, off, 64));
    return v;
}

__device__ __forceinline__ unsigned short f2bf(float x) {
    union { float f; unsigned u; } c; c.f = x;
    unsigned r = c.u + 0x7fffu + ((c.u >> 16) & 1u);   // RNE
    return (unsigned short)(r >> 16);
}

// LayerNorm one row of D=768 per block; 256 threads, 3 elems/thread.
__global__ __launch_bounds__(256) void ln_kernel(const float* __restrict__ x,
                                                 const float* __restrict__ w,
                                                 const float* __restrict__ bias,
                                                 float* __restrict__ y) {
    const int row = blockIdx.x;
    const int tid = threadIdx.x;
    const float* xr = x + (size_t)row * D;
    float* yr = y + (size_t)row * D;

    float v0 = xr[tid], v1 = xr[tid + 256], v2 = xr[tid + 512];

    __shared__ float red[4];
    const int wid = tid >> 6, lane = tid & 63;

    float s = wave_reduce_sum(v0 + v1 + v2);
    if (lane == 0) red[wid] = s;
    __syncthreads();
    const float mean = (red[0] + red[1] + red[2] + red[3]) * (1.0f / D);
    __syncthreads();

    const float d0 = v0 - mean, d1 = v1 - mean, d2 = v2 - mean;
    float ss = wave_reduce_sum(d0 * d0 + d1 * d1 + d2 * d2);
    if (lane == 0) red[wid] = ss;
    __syncthreads();
    const float var = (red[0] + red[1] + red[2] + red[3]) * (1.0f / D);
    const float rs = rsqrtf(var + EPS);

    yr[tid]       = d0 * rs * w[tid]       + bias[tid];
    yr[tid + 256] = d1 * rs * w[tid + 256] + bias[tid + 256];
    yr[tid + 512] = d2 * rs * w[tid + 512] + bias[tid + 512];
}

// Fused: LN(kv rows) + scores S[b][q][n] + bf16 frag-layout pack
// kvTf[b][dt:48][kt:7][slot:64][e:8] where value = kvn[kt*32+kg*8+e][dt*16+dl],
// slot = kg*16+dl. One block per (b, kt); 512 threads = 8 waves, 4 rows/wave.
__global__ __launch_bounds__(512) void kv_fused(const float* __restrict__ kv_x,
                                                const float* __restrict__ w,
                                                const float* __restrict__ bias,
                                                const float* __restrict__ qn,
                                                float* __restrict__ S,
                                                unsigned short* __restrict__ kvTf) {
    const int b  = blockIdx.x / KT;
    const int kt = blockIdx.x % KT;
    const int tid = threadIdx.x, wave = tid >> 6, lane = tid & 63;
    __shared__ unsigned short tile[32][TPAD];  // ~49.7 KB

    float qreg[NQ][12];
#pragma unroll
    for (int q = 0; q < NQ; ++q)
#pragma unroll
        for (int c = 0; c < 12; ++c) qreg[q][c] = qn[q * D + lane + 64 * c];

    for (int r = 0; r < 4; ++r) {
        const int nl = wave * 4 + r;
        const int n  = kt * 32 + nl;
        if (n < NP) {
            const float* xr = kv_x + ((size_t)b * NP + n) * D;
            float v[12];
            float s = 0.f;
#pragma unroll
            for (int c = 0; c < 12; ++c) { v[c] = xr[lane + 64 * c]; s += v[c]; }
            s = wave_reduce_sum(s);
            const float mean = s * (1.0f / D);
            float ss = 0.f;
#pragma unroll
            for (int c = 0; c < 12; ++c) { v[c] -= mean; ss += v[c] * v[c]; }
            ss = wave_reduce_sum(ss);
            const float rs = rsqrtf(ss * (1.0f / D) + EPS);
            float y[12];
#pragma unroll
            for (int c = 0; c < 12; ++c) {
                const int d = lane + 64 * c;
                y[c] = v[c] * rs * w[d] + bias[d];
                tile[nl][d] = f2bf(y[c]);
            }
#pragma unroll
            for (int q = 0; q < NQ; ++q) {
                float dq = 0.f;
#pragma unroll
                for (int c = 0; c < 12; ++c) dq += y[c] * qreg[q][c];
                dq = wave_reduce_sum(dq);
                if (lane == 0) S[((size_t)b * NQ + q) * NP + n] = dq * INV_SQRT_D;
            }
        } else {
#pragma unroll
            for (int c = 0; c < 12; ++c) tile[nl][lane + 64 * c] = 0;
        }
    }
    __syncthreads();

    // frag-layout store: 48 dt * 64 slots = 3072 chunks of 16B, 6 per thread.
#pragma unroll
    for (int rep = 0; rep < 6; ++rep) {
        const int chunk = rep * 512 + tid;
        const int dt = chunk >> 6, slot = chunk & 63;
        const int kg = slot >> 4, dl = slot & 15;
        short8 vals;
#pragma unroll
        for (int e = 0; e < 8; ++e)
            vals[e] = (short)tile[kg * 8 + e][dt * 16 + dl];
        *(short8*)(kvTf + ((((size_t)b * 48 + dt) * KT + kt) * 64 + slot) * 8) = vals;
    }
}

// Softmax prep -> TWO frag-layout copies:
// Abf0[i][mt][kt][slot][8] with stack row r0 = j*8+q  (i-stacked, pass 0)
// Abf1[j][mt][kt][slot][8] with stack row r1 = i*8+q  (j-stacked, pass 1)
// One block per ordered pair p; 4 waves x 2 q-rows, LDS transpose per row.
__global__ __launch_bounds__(256) void aprep(const float* __restrict__ S,
                                             unsigned short* __restrict__ Abf0,
                                             unsigned short* __restrict__ Abf1) {
    const int p = blockIdx.x, i = p >> 5, j = p & 31;
    const int tid = threadIdx.x, wave = tid >> 6, lane = tid & 63;
    __shared__ unsigned short lrow[4][KP];

    for (int rr = 0; rr < 2; ++rr) {
        const int q = wave * 2 + rr;
        const float* Si = S + ((size_t)i * NQ + q) * NP;
        const float* Sj = S + ((size_t)j * NQ + q) * NP;
        float v[4];
        float m = -1e30f;
#pragma unroll
        for (int c = 0; c < 4; ++c) {
            const int n = lane + 64 * c;
            v[c] = (n < NP) ? (Si[n] - Sj[n]) : -1e30f;
            m = fmaxf(m, v[c]);
        }
        m = wave_reduce_max(m);
        float e[4];
        float sum = 0.f;
#pragma unroll
        for (int c = 0; c < 4; ++c) {
            const int n = lane + 64 * c;
            e[c] = (n < NP) ? __expf(v[c] - m) : 0.f;
            sum += e[c];
        }
        sum = wave_reduce_sum(sum);
        const float rinv = 1.0f / sum;
#pragma unroll
        for (int c = 0; c < 4; ++c) {
            const int n = lane + 64 * c;
            if (n < KP) lrow[wave][n] = f2bf(e[c] * rinv);
        }
        __syncthreads();
        if (lane < 28) {
            const short8 vals = *(const short8*)(&lrow[wave][lane * 8]);
            const int kt = lane >> 2, kg = lane & 3;
            const int r0 = j * NQ + q, r1 = i * NQ + q;
            const int mt0 = r0 >> 4, dl0 = r0 & 15;
            const int mt1 = r1 >> 4, dl1 = r1 & 15;
            *(short8*)(Abf0 + ((((size_t)i * 16 + mt0) * KT + kt) * 64 + kg * 16 + dl0) * 8) = vals;
            *(short8*)(Abf1 + ((((size_t)j * 16 + mt1) * KT + kt) * 64 + kg * 16 + dl1) * 8) = vals;
        }
        __syncthreads();
    }
}

// Stacked-pair GEMM, operands in frag layout (1KB contiguous per wave-load).
// pass 0: out[b*256 + R] = A0-rows @ kv[b];  pass 1: out[row] -= A1 @ kv[b].
// M=256, K=224, N=96 per block; 8 waves, wave tile 64x48 (4x3 frags).
__global__ __launch_bounds__(512) void pair_gemm(const unsigned short* __restrict__ Abf,
                                                 const unsigned short* __restrict__ kvTf,
                                                 float* __restrict__ out, int pass) {
    const int b  = blockIdx.x >> 3;
    const int ns = blockIdx.x & 7;
    const int tid = threadIdx.x, wave = tid >> 6, lane = tid & 63;
    const int wm = wave & 3, wn = wave >> 2;
    const int dlow = lane & 15, kgrp = lane >> 4;

    const unsigned short* Ab = Abf + (size_t)b * 16 * KT * 512 + lane * 8;
    const unsigned short* Bb = kvTf + ((size_t)b * 48 + ns * 6 + wn * 3) * KT * 512 + lane * 8;

    f32x4 acc[4][3];
#pragma unroll
    for (int m = 0; m < 4; ++m)
#pragma unroll
        for (int n = 0; n < 3; ++n) {
            f32x4 z = {0.f, 0.f, 0.f, 0.f};
            acc[m][n] = z;
        }

    short8 Af[4], Bf[3];
#pragma unroll
    for (int m = 0; m < 4; ++m) Af[m] = *(const short8*)(Ab + ((wm * 4 + m) * KT) * 512);
#pragma unroll
    for (int n = 0; n < 3; ++n) Bf[n] = *(const short8*)(Bb + (n * KT) * 512);

#pragma unroll
    for (int kt = 0; kt < KT; ++kt) {
        short8 An[4], Bn[3];
        if (kt + 1 < KT) {
#pragma unroll
            for (int m = 0; m < 4; ++m) An[m] = *(const short8*)(Ab + ((wm * 4 + m) * KT + kt + 1) * 512);
#pragma unroll
            for (int n = 0; n < 3; ++n) Bn[n] = *(const short8*)(Bb + (n * KT + kt + 1) * 512);
        }
#pragma unroll
        for (int m = 0; m < 4; ++m)
#pragma unroll
            for (int n = 0; n < 3; ++n)
                acc[m][n] = __builtin_amdgcn_mfma_f32_16x16x32_bf16(Af[m], Bf[n], acc[m][n], 0, 0, 0);
        if (kt + 1 < KT) {
#pragma unroll
            for (int m = 0; m < 4; ++m) Af[m] = An[m];
#pragma unroll
            for (int n = 0; n < 3; ++n) Bf[n] = Bn[n];
        }
    }

    // C layout: col = lane&15 (d), row-in-frag = kgrp*4 + reg
#pragma unroll
    for (int m = 0; m < 4; ++m) {
#pragma unroll
        for (int reg = 0; reg < 4; ++reg) {
            const int R = wm * 64 + m * 16 + kgrp * 4 + reg;
            const int arow = (pass == 0) ? (b * 256 + R)
                                         : ((R >> 3) * 256 + b * NQ + (R & 7));
            float* op = out + (size_t)arow * D + ns * 96 + wn * 48 + dlow;
            if (pass == 0) {
#pragma unroll
                for (int n = 0; n < 3; ++n) op[n * 16] = acc[m][n][reg];
            } else {
#pragma unroll
                for (int n = 0; n < 3; ++n) op[n * 16] = op[n * 16] - acc[m][n][reg];
            }
        }
    }
}

extern "C" void kernel_launch(void* const* d_in, const int* in_sizes, int n_in,
                              void* d_out, int out_size, void* d_ws, size_t ws_size,
                              hipStream_t stream) {
    const float* q_x     = (const float*)d_in[0];
    const float* kv_x    = (const float*)d_in[1];
    const float* ln_q_w  = (const float*)d_in[2];
    const float* ln_q_b  = (const float*)d_in[3];
    const float* ln_kv_w = (const float*)d_in[4];
    const float* ln_kv_b = (const float*)d_in[5];
    float* out = (float*)d_out;

    float* ws = (float*)d_ws;
    float* qn = ws;                               // 8*768 f32
    float* S  = ws + NQ * D;                      // 32*8*196 f32
    unsigned short* kvTf = (unsigned short*)(ws + NQ * D + B * NQ * NP);  // 32*48*7*512
    unsigned short* Abf0 = kvTf + (size_t)B * 48 * KT * 512;              // 32*16*7*512
    unsigned short* Abf1 = Abf0 + (size_t)B * 16 * KT * 512;

    ln_kernel<<<NQ, 256, 0, stream>>>(q_x, ln_q_w, ln_q_b, qn);
    kv_fused<<<B * KT, 512, 0, stream>>>(kv_x, ln_kv_w, ln_kv_b, qn, S, kvTf);
    aprep<<<B * B, 256, 0, stream>>>(S, Abf0, Abf1);
    pair_gemm<<<B * 8, 512, 0, stream>>>(Abf0, kvTf, out, 0);
    pair_gemm<<<B * 8, 512, 0, stream>>>(Abf1, kvTf, out, 1);
}

// Round 6
// 57.039 us; speedup vs baseline: 1.8138x; 1.0449x over previous
//
#include <hip/hip_runtime.h>
#include <math.h>

constexpr int D  = 768;
constexpr int NQ = 8;
constexpr int B  = 32;
constexpr int NP = 196;      // n_patch
constexpr int KT = 7;        // K tiles of 32
constexpr int KP = KT * 32;  // 224 padded K
constexpr int TPAD = 776;    // LDS tile row stride (shorts)
constexpr float EPS = 1e-5f;
constexpr float INV_SQRT_D = 0.036084391824351615f;  // 1/sqrt(768)

typedef __attribute__((ext_vector_type(8))) short short8;
typedef __attribute__((ext_vector_type(4))) float f32x4;

__device__ __forceinline__ float wave_reduce_sum(float v) {
#pragma unroll
    for (int off = 32; off > 0; off >>= 1) v += __shfl_xor(v, off, 64);
    return v;
}
__device__ __forceinline__ float wave_reduce_max(float v) {
#pragma unroll
    for (int off = 32; off > 0; off >>= 1) v = fmaxf(v, __shfl_xor(v, off, 64));
    return v;
}

__device__ __forceinline__ unsigned short f2bf(float x) {
    union { float f; unsigned u; } c; c.f = x;
    unsigned r = c.u + 0x7fffu + ((c.u >> 16) & 1u);   // RNE
    return (unsigned short)(r >> 16);
}

// Fused: LN(q) in-reg + LN(kv 16-row half-tile) + scores S + frag-layout pack.
// kvTf[b][dt:48][kt:7][slot:64][e:8], value = kvn[kt*32+kg*8+e][dt*16+dl],
// slot = kg*16+dl.  One block per (b, h) with h in [0,14): rows [h*16,h*16+16).
__global__ __launch_bounds__(256) void kv_fused(const float* __restrict__ q_x,
                                                const float* __restrict__ qw,
                                                const float* __restrict__ qb,
                                                const float* __restrict__ kv_x,
                                                const float* __restrict__ kw,
                                                const float* __restrict__ kb,
                                                float* __restrict__ S,
                                                unsigned short* __restrict__ kvTf) {
    const int b = blockIdx.x / 14;
    const int h = blockIdx.x % 14;
    const int kt = h >> 1;
    const int kgbase = (h & 1) * 2;
    const int tid = threadIdx.x, wave = tid >> 6, lane = tid & 63;
    __shared__ unsigned short tile[16][TPAD];  // 24.8 KB

    const bool live = (h * 16) < NP;

    float wv[12], bv[12];
#pragma unroll
    for (int c = 0; c < 12; ++c) { wv[c] = kw[lane + 64 * c]; bv[c] = kb[lane + 64 * c]; }

    float qreg[NQ][12];
    if (live) {
        float wqv[12], bqv[12];
#pragma unroll
        for (int c = 0; c < 12; ++c) { wqv[c] = qw[lane + 64 * c]; bqv[c] = qb[lane + 64 * c]; }
#pragma unroll
        for (int q = 0; q < NQ; ++q) {
            float v[12];
            float s = 0.f;
#pragma unroll
            for (int c = 0; c < 12; ++c) { v[c] = q_x[q * D + lane + 64 * c]; s += v[c]; }
            s = wave_reduce_sum(s);
            const float mean = s * (1.0f / D);
            float ss = 0.f;
#pragma unroll
            for (int c = 0; c < 12; ++c) { v[c] -= mean; ss += v[c] * v[c]; }
            ss = wave_reduce_sum(ss);
            const float rs = rsqrtf(ss * (1.0f / D) + EPS);
#pragma unroll
            for (int c = 0; c < 12; ++c) qreg[q][c] = v[c] * rs * wqv[c] + bqv[c];
        }
    }

    for (int r = 0; r < 4; ++r) {
        const int nl = wave * 4 + r;
        const int n  = h * 16 + nl;
        if (n < NP) {
            const float* xr = kv_x + ((size_t)b * NP + n) * D;
            float v[12];
            float s = 0.f;
#pragma unroll
            for (int c = 0; c < 12; ++c) { v[c] = xr[lane + 64 * c]; s += v[c]; }
            s = wave_reduce_sum(s);
            const float mean = s * (1.0f / D);
            float ss = 0.f;
#pragma unroll
            for (int c = 0; c < 12; ++c) { v[c] -= mean; ss += v[c] * v[c]; }
            ss = wave_reduce_sum(ss);
            const float rs = rsqrtf(ss * (1.0f / D) + EPS);
            float y[12];
#pragma unroll
            for (int c = 0; c < 12; ++c) {
                y[c] = v[c] * rs * wv[c] + bv[c];
                tile[nl][lane + 64 * c] = f2bf(y[c]);
            }
#pragma unroll
            for (int q = 0; q < NQ; ++q) {
                float dq = 0.f;
#pragma unroll
                for (int c = 0; c < 12; ++c) dq += y[c] * qreg[q][c];
                dq = wave_reduce_sum(dq);
                if (lane == 0) S[((size_t)b * NQ + q) * NP + n] = dq * INV_SQRT_D;
            }
        } else {
#pragma unroll
            for (int c = 0; c < 12; ++c) tile[nl][lane + 64 * c] = 0;
        }
    }
    __syncthreads();

    // frag-layout store: 48 dt * 32 local slots = 1536 chunks of 16B, 6/thread.
#pragma unroll
    for (int rep = 0; rep < 6; ++rep) {
        const int chunk = rep * 256 + tid;
        const int dt = chunk >> 5, ls = chunk & 31;
        const int hi = ls >> 4, dl = ls & 15;
        const int kg = kgbase + hi;
        short8 vals;
#pragma unroll
        for (int e = 0; e < 8; ++e)
            vals[e] = (short)tile[hi * 8 + e][dt * 16 + dl];
        *(short8*)(kvTf + ((((size_t)b * 48 + dt) * KT + kt) * 64 + kg * 16 + dl) * 8) = vals;
    }
}

// Softmax prep -> TWO frag-layout copies:
// Abf0[i][mt][kt][slot][8] stack row r0 = j*8+q  (i-stacked, pass 0)
// Abf1[j][mt][kt][slot][8] stack row r1 = i*8+q  (j-stacked, pass 1)
// One block per ordered pair p; 8 waves, 1 q-row each; one barrier.
__global__ __launch_bounds__(512) void aprep(const float* __restrict__ S,
                                             unsigned short* __restrict__ Abf0,
                                             unsigned short* __restrict__ Abf1) {
    const int p = blockIdx.x, i = p >> 5, j = p & 31;
    const int tid = threadIdx.x, wave = tid >> 6, lane = tid & 63;
    __shared__ unsigned short lrow[NQ][KP];  // 3.6 KB

    const int q = wave;
    const float* Si = S + ((size_t)i * NQ + q) * NP;
    const float* Sj = S + ((size_t)j * NQ + q) * NP;
    float v[4];
    float m = -1e30f;
#pragma unroll
    for (int c = 0; c < 4; ++c) {
        const int n = lane + 64 * c;
        v[c] = (n < NP) ? (Si[n] - Sj[n]) : -1e30f;
        m = fmaxf(m, v[c]);
    }
    m = wave_reduce_max(m);
    float e[4];
    float sum = 0.f;
#pragma unroll
    for (int c = 0; c < 4; ++c) {
        const int n = lane + 64 * c;
        e[c] = (n < NP) ? __expf(v[c] - m) : 0.f;
        sum += e[c];
    }
    sum = wave_reduce_sum(sum);
    const float rinv = 1.0f / sum;
#pragma unroll
    for (int c = 0; c < 4; ++c) {
        const int n = lane + 64 * c;
        if (n < KP) lrow[q][n] = f2bf(e[c] * rinv);
    }
    __syncthreads();

    if (tid < NQ * 28) {
        const int q2 = tid / 28, c = tid % 28;
        const int kt = c >> 2, kg = c & 3;
        const short8 vals = *(const short8*)(&lrow[q2][c * 8]);
        const int r0 = j * NQ + q2, r1 = i * NQ + q2;
        *(short8*)(Abf0 + ((((size_t)i * 16 + (r0 >> 4)) * KT + kt) * 64 + kg * 16 + (r0 & 15)) * 8) = vals;
        *(short8*)(Abf1 + ((((size_t)j * 16 + (r1 >> 4)) * KT + kt) * 64 + kg * 16 + (r1 & 15)) * 8) = vals;
    }
}

// Stacked-pair GEMM, frag-layout operands (1KB contiguous per wave-load).
// PASS 0: out[b*256 + R] = A0-rows @ kv[b]
// PASS 1: out[(R>>3)*256 + b*8 + (R&7)] -= A1-rows @ kv[b]
// M=256, K=224, N=96 per block; 16 waves, wave tile 32x48 (2x3 frags).
template <int PASS>
__global__ __launch_bounds__(1024) void pair_gemm(const unsigned short* __restrict__ Abf,
                                                  const unsigned short* __restrict__ kvTf,
                                                  float* __restrict__ out) {
    const int b  = blockIdx.x >> 3;
    const int ns = blockIdx.x & 7;
    const int tid = threadIdx.x, wave = tid >> 6, lane = tid & 63;
    const int wm = wave & 7, wn = wave >> 3;
    const int dlow = lane & 15, kgrp = lane >> 4;

    const unsigned short* Ab = Abf + (size_t)b * 16 * KT * 512 + (size_t)lane * 8;
    const unsigned short* Bb = kvTf + ((size_t)b * 48 + ns * 6 + wn * 3) * KT * 512 + (size_t)lane * 8;

    // pass-1: preload the RMW targets early so the read hides under the K loop
    float cpre[2][4][3];
    if (PASS == 1) {
#pragma unroll
        for (int m = 0; m < 2; ++m)
#pragma unroll
            for (int reg = 0; reg < 4; ++reg) {
                const int R = wm * 32 + m * 16 + kgrp * 4 + reg;
                const int arow = (R >> 3) * 256 + b * NQ + (R & 7);
                const float* op = out + (size_t)arow * D + ns * 96 + wn * 48 + dlow;
#pragma unroll
                for (int n = 0; n < 3; ++n) cpre[m][reg][n] = op[n * 16];
            }
    }

    f32x4 acc[2][3];
#pragma unroll
    for (int m = 0; m < 2; ++m)
#pragma unroll
        for (int n = 0; n < 3; ++n) {
            f32x4 z = {0.f, 0.f, 0.f, 0.f};
            acc[m][n] = z;
        }

    short8 Af[2], Bf[3];
#pragma unroll
    for (int m = 0; m < 2; ++m) Af[m] = *(const short8*)(Ab + ((wm * 2 + m) * KT) * 512);
#pragma unroll
    for (int n = 0; n < 3; ++n) Bf[n] = *(const short8*)(Bb + (n * KT) * 512);

#pragma unroll
    for (int kt = 0; kt < KT; ++kt) {
        short8 An[2], Bn[3];
        if (kt + 1 < KT) {
#pragma unroll
            for (int m = 0; m < 2; ++m) An[m] = *(const short8*)(Ab + ((wm * 2 + m) * KT + kt + 1) * 512);
#pragma unroll
            for (int n = 0; n < 3; ++n) Bn[n] = *(const short8*)(Bb + (n * KT + kt + 1) * 512);
        }
#pragma unroll
        for (int m = 0; m < 2; ++m)
#pragma unroll
            for (int n = 0; n < 3; ++n)
                acc[m][n] = __builtin_amdgcn_mfma_f32_16x16x32_bf16(Af[m], Bf[n], acc[m][n], 0, 0, 0);
        if (kt + 1 < KT) {
#pragma unroll
            for (int m = 0; m < 2; ++m) Af[m] = An[m];
#pragma unroll
            for (int n = 0; n < 3; ++n) Bf[n] = Bn[n];
        }
    }

    // C layout: col = lane&15 (d), row-in-frag = kgrp*4 + reg
#pragma unroll
    for (int m = 0; m < 2; ++m) {
#pragma unroll
        for (int reg = 0; reg < 4; ++reg) {
            const int R = wm * 32 + m * 16 + kgrp * 4 + reg;
            const int arow = (PASS == 0) ? (b * 256 + R)
                                         : ((R >> 3) * 256 + b * NQ + (R & 7));
            float* op = out + (size_t)arow * D + ns * 96 + wn * 48 + dlow;
            if (PASS == 0) {
#pragma unroll
                for (int n = 0; n < 3; ++n) op[n * 16] = acc[m][n][reg];
            } else {
#pragma unroll
                for (int n = 0; n < 3; ++n) op[n * 16] = cpre[m][reg][n] - acc[m][n][reg];
            }
        }
    }
}

extern "C" void kernel_launch(void* const* d_in, const int* in_sizes, int n_in,
                              void* d_out, int out_size, void* d_ws, size_t ws_size,
                              hipStream_t stream) {
    const float* q_x     = (const float*)d_in[0];
    const float* kv_x    = (const float*)d_in[1];
    const float* ln_q_w  = (const float*)d_in[2];
    const float* ln_q_b  = (const float*)d_in[3];
    const float* ln_kv_w = (const float*)d_in[4];
    const float* ln_kv_b = (const float*)d_in[5];
    float* out = (float*)d_out;

    float* ws = (float*)d_ws;
    float* S  = ws;                                            // 32*8*196 f32
    unsigned short* kvTf = (unsigned short*)(ws + B * NQ * NP); // 32*48*7*512 bf16
    unsigned short* Abf0 = kvTf + (size_t)B * 48 * KT * 512;    // 32*16*7*512 bf16
    unsigned short* Abf1 = Abf0 + (size_t)B * 16 * KT * 512;

    kv_fused<<<B * 14, 256, 0, stream>>>(q_x, ln_q_w, ln_q_b, kv_x, ln_kv_w, ln_kv_b, S, kvTf);
    aprep<<<B * B, 512, 0, stream>>>(S, Abf0, Abf1);
    pair_gemm<0><<<B * 8, 1024, 0, stream>>>(Abf0, kvTf, out);
    pair_gemm<1><<<B * 8, 1024, 0, stream>>>(Abf1, kvTf, out);
}

// Round 7
// 54.639 us; speedup vs baseline: 1.8935x; 1.0439x over previous
//
#include <hip/hip_runtime.h>
#include <math.h>

constexpr int D  = 768;
constexpr int NQ = 8;
constexpr int B  = 32;
constexpr int NP = 196;      // n_patch
constexpr int KT = 7;        // K tiles of 32
constexpr int KP = KT * 32;  // 224 padded K
constexpr int TPAD = 776;    // LDS tile row stride (shorts)
constexpr int NPAIR = (B * (B - 1)) / 2;  // 496 unordered pairs
constexpr float EPS = 1e-5f;
constexpr float INV_SQRT_D = 0.036084391824351615f;  // 1/sqrt(768)

typedef __attribute__((ext_vector_type(8))) short short8;
typedef __attribute__((ext_vector_type(4))) float f32x4;

__device__ __forceinline__ float wave_reduce_sum(float v) {
#pragma unroll
    for (int off = 32; off > 0; off >>= 1) v += __shfl_xor(v, off, 64);
    return v;
}
__device__ __forceinline__ float wave_reduce_max(float v) {
#pragma unroll
    for (int off = 32; off > 0; off >>= 1) v = fmaxf(v, __shfl_xor(v, off, 64));
    return v;
}

__device__ __forceinline__ unsigned short f2bf(float x) {
    union { float f; unsigned u; } c; c.f = x;
    unsigned r = c.u + 0x7fffu + ((c.u >> 16) & 1u);   // RNE
    return (unsigned short)(r >> 16);
}

// Fused: LN(q) in-reg + LN(kv 16-row half-tile) + scores S + frag-layout pack.
// kvTf[b][dt:48][kt:7][slot:64][e:8], value = kvn[kt*32+kg*8+e][dt*16+dl],
// slot = kg*16+dl.  One block per (b, h) with h in [0,14): rows [h*16,h*16+16).
__global__ __launch_bounds__(256) void kv_fused(const float* __restrict__ q_x,
                                                const float* __restrict__ qw,
                                                const float* __restrict__ qb,
                                                const float* __restrict__ kv_x,
                                                const float* __restrict__ kw,
                                                const float* __restrict__ kb,
                                                float* __restrict__ S,
                                                unsigned short* __restrict__ kvTf) {
    const int b = blockIdx.x / 14;
    const int h = blockIdx.x % 14;
    const int kt = h >> 1;
    const int kgbase = (h & 1) * 2;
    const int tid = threadIdx.x, wave = tid >> 6, lane = tid & 63;
    __shared__ unsigned short tile[16][TPAD];  // 24.8 KB

    const bool live = (h * 16) < NP;

    float wv[12], bv[12];
#pragma unroll
    for (int c = 0; c < 12; ++c) { wv[c] = kw[lane + 64 * c]; bv[c] = kb[lane + 64 * c]; }

    float qreg[NQ][12];
    if (live) {
        float wqv[12], bqv[12];
#pragma unroll
        for (int c = 0; c < 12; ++c) { wqv[c] = qw[lane + 64 * c]; bqv[c] = qb[lane + 64 * c]; }
#pragma unroll
        for (int q = 0; q < NQ; ++q) {
            float v[12];
            float s = 0.f;
#pragma unroll
            for (int c = 0; c < 12; ++c) { v[c] = q_x[q * D + lane + 64 * c]; s += v[c]; }
            s = wave_reduce_sum(s);
            const float mean = s * (1.0f / D);
            float ss = 0.f;
#pragma unroll
            for (int c = 0; c < 12; ++c) { v[c] -= mean; ss += v[c] * v[c]; }
            ss = wave_reduce_sum(ss);
            const float rs = rsqrtf(ss * (1.0f / D) + EPS);
#pragma unroll
            for (int c = 0; c < 12; ++c) qreg[q][c] = v[c] * rs * wqv[c] + bqv[c];
        }
    }

    for (int r = 0; r < 4; ++r) {
        const int nl = wave * 4 + r;
        const int n  = h * 16 + nl;
        if (n < NP) {
            const float* xr = kv_x + ((size_t)b * NP + n) * D;
            float v[12];
            float s = 0.f;
#pragma unroll
            for (int c = 0; c < 12; ++c) { v[c] = xr[lane + 64 * c]; s += v[c]; }
            s = wave_reduce_sum(s);
            const float mean = s * (1.0f / D);
            float ss = 0.f;
#pragma unroll
            for (int c = 0; c < 12; ++c) { v[c] -= mean; ss += v[c] * v[c]; }
            ss = wave_reduce_sum(ss);
            const float rs = rsqrtf(ss * (1.0f / D) + EPS);
            float y[12];
#pragma unroll
            for (int c = 0; c < 12; ++c) {
                y[c] = v[c] * rs * wv[c] + bv[c];
                tile[nl][lane + 64 * c] = f2bf(y[c]);
            }
#pragma unroll
            for (int q = 0; q < NQ; ++q) {
                float dq = 0.f;
#pragma unroll
                for (int c = 0; c < 12; ++c) dq += y[c] * qreg[q][c];
                dq = wave_reduce_sum(dq);
                if (lane == 0) S[((size_t)b * NQ + q) * NP + n] = dq * INV_SQRT_D;
            }
        } else {
#pragma unroll
            for (int c = 0; c < 12; ++c) tile[nl][lane + 64 * c] = 0;
        }
    }
    __syncthreads();

    // frag-layout store: 48 dt * 32 local slots = 1536 chunks of 16B, 6/thread.
#pragma unroll
    for (int rep = 0; rep < 6; ++rep) {
        const int chunk = rep * 256 + tid;
        const int dt = chunk >> 5, ls = chunk & 31;
        const int hi = ls >> 4, dl = ls & 15;
        const int kg = kgbase + hi;
        short8 vals;
#pragma unroll
        for (int e = 0; e < 8; ++e)
            vals[e] = (short)tile[hi * 8 + e][dt * 16 + dl];
        *(short8*)(kvTf + ((((size_t)b * 48 + dt) * KT + kt) * 64 + kg * 16 + dl) * 8) = vals;
    }
}

// One-pass unordered-pair GEMM with fused softmax.
// Block u < 496: pair {i<j}. 16 waves. M-tile rows r = dir*8+q:
//   dir0 = P_ij = softmax(S_i - S_j), dir1 = P_ji = softmax(S_j - S_i).
// acc = A @ kv_i + (-A) @ kv_j  (f32 accumulation of the pair difference).
// Write rows dir0 -> out[i*32+j], rows dir1 -> -acc at out[j*32+i].
// Blocks u >= 496: zero the 32 diagonal pair outputs.
__global__ __launch_bounds__(1024, 4) void dgemm(const float* __restrict__ S,
                                                 const unsigned short* __restrict__ kvTf,
                                                 float* __restrict__ out) {
    const int u = blockIdx.x;
    const int tid = threadIdx.x, wave = tid >> 6, lane = tid & 63;

    if (u >= NPAIR) {                       // diagonal pairs: exact zero
        const int d = u - NPAIR;
        float* base = out + (size_t)(d * (B + 1)) * NQ * D;
        for (int t = tid; t < NQ * D; t += 1024) base[t] = 0.f;
        return;
    }

    int uu = u, i = 0;
    while (uu >= 31 - i) { uu -= 31 - i; ++i; }
    const int j = i + 1 + uu;

    __shared__ unsigned short a2[KT][64][8];  // 7 KB, A frags for 16 rows

    // ---- softmax: one row per wave; row r = wave = dir*8+q ----
    {
        const int dir = wave >> 3, q = wave & 7;
        const float* Sa = S + ((size_t)(dir ? j : i) * NQ + q) * NP;
        const float* Sb = S + ((size_t)(dir ? i : j) * NQ + q) * NP;
        float v[4];
        float m = -1e30f;
#pragma unroll
        for (int c = 0; c < 4; ++c) {
            const int n = lane + 64 * c;
            v[c] = (n < NP) ? (Sa[n] - Sb[n]) : -1e30f;
            m = fmaxf(m, v[c]);
        }
        m = wave_reduce_max(m);
        float e[4];
        float sum = 0.f;
#pragma unroll
        for (int c = 0; c < 4; ++c) {
            const int n = lane + 64 * c;
            e[c] = (n < NP) ? __expf(v[c] - m) : 0.f;
            sum += e[c];
        }
        sum = wave_reduce_sum(sum);
        const float rinv = 1.0f / sum;
#pragma unroll
        for (int c = 0; c < 4; ++c) {
            const int n = lane + 64 * c;
            if (n < KP) {
                const unsigned short w16 = (n < NP) ? f2bf(e[c] * rinv) : (unsigned short)0;
                a2[n >> 5][((n >> 3) & 3) * 16 + wave][n & 7] = w16;
            }
        }
    }
    __syncthreads();

    // ---- K loop: wave covers cols [wave*48, wave*48+48) ----
    const unsigned short* Ki = kvTf + (size_t)i * 48 * KT * 512 + (size_t)lane * 8;
    const unsigned short* Kj = kvTf + (size_t)j * 48 * KT * 512 + (size_t)lane * 8;

    f32x4 acc[3];
#pragma unroll
    for (int nf = 0; nf < 3; ++nf) {
        f32x4 z = {0.f, 0.f, 0.f, 0.f};
        acc[nf] = z;
    }

#pragma unroll
    for (int kt = 0; kt < KT; ++kt) {
        short8 a = *(const short8*)(&a2[kt][lane][0]);
        short8 na;
#pragma unroll
        for (int e = 0; e < 8; ++e) na[e] = (short)(a[e] ^ (short)0x8000);
#pragma unroll
        for (int nf = 0; nf < 3; ++nf) {
            const int dt = wave * 3 + nf;
            short8 ki = *(const short8*)(Ki + ((size_t)dt * KT + kt) * 512);
            short8 kj = *(const short8*)(Kj + ((size_t)dt * KT + kt) * 512);
            acc[nf] = __builtin_amdgcn_mfma_f32_16x16x32_bf16(a,  ki, acc[nf], 0, 0, 0);
            acc[nf] = __builtin_amdgcn_mfma_f32_16x16x32_bf16(na, kj, acc[nf], 0, 0, 0);
        }
    }

    // ---- epilogue: C row-in-tile = (lane>>4)*4 + reg, col = lane&15 ----
    const int kgrp = lane >> 4, dl = lane & 15;
    const int pij = i * B + j, pji = j * B + i;
#pragma unroll
    for (int reg = 0; reg < 4; ++reg) {
        const int r = kgrp * 4 + reg;
        const int dirr = r >> 3, qq = r & 7;
        const int p = dirr ? pji : pij;
        const float sgn = dirr ? -1.f : 1.f;
        float* op = out + ((size_t)p * NQ + qq) * D + wave * 48 + dl;
#pragma unroll
        for (int nf = 0; nf < 3; ++nf) op[nf * 16] = sgn * acc[nf][reg];
    }
}

extern "C" void kernel_launch(void* const* d_in, const int* in_sizes, int n_in,
                              void* d_out, int out_size, void* d_ws, size_t ws_size,
                              hipStream_t stream) {
    const float* q_x     = (const float*)d_in[0];
    const float* kv_x    = (const float*)d_in[1];
    const float* ln_q_w  = (const float*)d_in[2];
    const float* ln_q_b  = (const float*)d_in[3];
    const float* ln_kv_w = (const float*)d_in[4];
    const float* ln_kv_b = (const float*)d_in[5];
    float* out = (float*)d_out;

    float* ws = (float*)d_ws;
    float* S  = ws;                                             // 32*8*196 f32
    unsigned short* kvTf = (unsigned short*)(ws + B * NQ * NP);  // 32*48*7*512 bf16

    kv_fused<<<B * 14, 256, 0, stream>>>(q_x, ln_q_w, ln_q_b, kv_x, ln_kv_w, ln_kv_b, S, kvTf);
    dgemm<<<NPAIR + B, 1024, 0, stream>>>(S, kvTf, out);
}